// Round 8
// baseline (154.072 us; speedup 1.0000x reference)
//
#include <hip/hip_runtime.h>

typedef __attribute__((ext_vector_type(8))) __bf16 bf16x8;
typedef __attribute__((ext_vector_type(4))) __bf16 bf16x4;
typedef __attribute__((ext_vector_type(4))) float f32x4;

#define D_OUT 4096
#define D_IN  4096
#define RANK  512
#define MROWS 8192   // BATCH*SEQ

__device__ __forceinline__ void gload_lds16(const void* gsrc, void* ldst) {
  __builtin_amdgcn_global_load_lds(
      (const __attribute__((address_space(1))) void*)gsrc,
      (__attribute__((address_space(3))) void*)ldst, 16, 0, 0);
}

// ---------------- f32 -> bf16 elementwise convert (A) ----------------
__global__ __launch_bounds__(256) void cvt_f32_bf16(const float* __restrict__ in,
                                                    __bf16* __restrict__ out,
                                                    size_t n) {
  size_t i = ((size_t)blockIdx.x * 256 + threadIdx.x) * 4;
  size_t stride = (size_t)gridDim.x * 256 * 4;
  for (; i < n; i += stride) {
    float4 v = *(const float4*)(in + i);
    bf16x4 o = {(__bf16)v.x, (__bf16)v.y, (__bf16)v.z, (__bf16)v.w};
    *(bf16x4*)(out + i) = o;
  }
}

// ------------- f32 [R][C] -> bf16 [C][R] transpose-convert (B) -------------
__global__ __launch_bounds__(256) void transpose_cvt(const float* __restrict__ in,
                                                     __bf16* __restrict__ out,
                                                     int R, int C) {
  __shared__ __bf16 tile[64][72];
  const int r0 = blockIdx.x * 64, c0 = blockIdx.y * 64;
  const int t = threadIdx.x;
  const int tr = t / 16, tc4 = (t % 16) * 4;
#pragma unroll
  for (int i = 0; i < 4; ++i) {
    int r = i * 16 + tr;
    float4 v = *(const float4*)(in + (size_t)(r0 + r) * C + c0 + tc4);
    tile[r][tc4 + 0] = (__bf16)v.x;
    tile[r][tc4 + 1] = (__bf16)v.y;
    tile[r][tc4 + 2] = (__bf16)v.z;
    tile[r][tc4 + 3] = (__bf16)v.w;
  }
  __syncthreads();
#pragma unroll
  for (int i = 0; i < 4; ++i) {
    int c = i * 16 + tr;
    bf16x4 o = {tile[tc4 + 0][c], tile[tc4 + 1][c], tile[tc4 + 2][c], tile[tc4 + 3][c]};
    *(bf16x4*)(out + (size_t)(c0 + c) * R + r0 + tc4) = o;
  }
}

// ---------------- partial-sum reduce + cvt: o = bf16(t0 + t1) ----------------
__global__ __launch_bounds__(256) void reduce2_bf16(const __bf16* __restrict__ t0,
                                                    const __bf16* __restrict__ t1,
                                                    __bf16* __restrict__ o) {
  size_t i = ((size_t)blockIdx.x * 256 + threadIdx.x) * 8;
  bf16x8 a = *(const bf16x8*)(t0 + i);
  bf16x8 b = *(const bf16x8*)(t1 + i);
  bf16x8 r;
#pragma unroll
  for (int j = 0; j < 8; ++j) r[j] = (__bf16)((float)a[j] + (float)b[j]);
  *(bf16x8*)(o + i) = r;
}

// ==================== GEMM1: counted-vmcnt 2-phase pipeline ====================
// C[M,N] = bf16(Xf32[M,:]) @ Bmat[N,:]^T (bf16 partials per z-slice).
// BK=32, dbuf LDS 48 KB (A f32 16K x2 + B bf16 8K x2) -> 3 blocks/CU.
// Per tile: ds_read frags(t) | lgkmcnt(0)+sched_barrier | s_barrier |
// STAGE(t+2 -> freed buf) | 16 MFMA | vmcnt(6) | s_barrier.  vmcnt never 0
// mid-loop: tile t+1's 6 loads retire under tile t's compute (T3+T4).
__global__ __launch_bounds__(256) void gemm1_pipe(const float* __restrict__ Xf,
                                                  const __bf16* __restrict__ Bmat,
                                                  __bf16* __restrict__ Cout,
                                                  int M, int N, int Kred, int ldk) {
  constexpr int BM = 128, BN = 128, BK = 32;
  constexpr int MI = 4, NI = 4;   // per-wave 64x64, 2x2 waves
  __shared__ alignas(16) float  Af[2][BM * BK];
  __shared__ alignas(16) __bf16 Bl[2][BN * BK];

  const int tid = threadIdx.x;
  const int wid = tid >> 6;
  const int lane = tid & 63;
  const int l15 = lane & 15, lhi = lane >> 4;
  const int wr = wid >> 1, wc = wid & 1;

  const int m0 = blockIdx.x * BM;
  const int n0 = blockIdx.y * BN;
  const int kbase = blockIdx.z * Kred;
  const int nt = Kred / BK;   // 64

  f32x4 acc[MI][NI] = {};

  auto stage = [&](int t, int c) {
    const int k0 = kbase + t * BK;
    // A tile f32 [128][32]: 4 issues; phys block b holds logical b^(row&7)
#pragma unroll
    for (int it = 0; it < 4; ++it) {
      int o = (it * 256 + tid) * 4;
      int row = o >> 5;
      int b = (o & 31) >> 2;
      int colsw = (b ^ (row & 7)) * 4;
      gload_lds16(Xf + (size_t)(m0 + row) * ldk + k0 + colsw,
                  &Af[c][(it * 256 + wid * 64) * 4]);
    }
    // B tile bf16 [128][32]: 2 issues; phys block b holds logical b^((row>>1)&3)
#pragma unroll
    for (int it = 0; it < 2; ++it) {
      int o = (it * 256 + tid) * 8;
      int row = o >> 5;
      int b = (o & 31) >> 3;
      int colsw = (b ^ ((row >> 1) & 3)) * 8;
      gload_lds16(Bmat + (size_t)(n0 + row) * ldk + k0 + colsw,
                  &Bl[c][(it * 256 + wid * 64) * 8]);
    }
  };

  // prologue: tiles 0,1 in flight; wait tile 0 (6 of 12 outstanding)
  stage(0, 0);
  stage(1, 1);
  asm volatile("s_waitcnt vmcnt(6)" ::: "memory");
  __builtin_amdgcn_s_barrier();

  for (int t = 0; t < nt; ++t) {
    const int c = t & 1;
    // ---- fragment reads from buf c (+ f32->bf16 convert for A) ----
    bf16x8 af[MI];
    bf16x8 bfv[NI];
#pragma unroll
    for (int mi = 0; mi < MI; ++mi) {
      int row = wr * 64 + mi * 16 + l15;
      int p0 = (lhi * 2) ^ (row & 7);
      const char* base = (const char*)&Af[c][0] + row * 128;
      f32x4 a0 = *(const f32x4*)(base + p0 * 16);
      f32x4 a1 = *(const f32x4*)(base + (p0 ^ 1) * 16);
#pragma unroll
      for (int j = 0; j < 4; ++j) {
        af[mi][j]     = (__bf16)a0[j];
        af[mi][4 + j] = (__bf16)a1[j];
      }
    }
#pragma unroll
    for (int ni = 0; ni < NI; ++ni) {
      int row = wc * 64 + ni * 16 + l15;
      int p = lhi ^ ((row >> 1) & 3);
      bfv[ni] = *(const bf16x8*)((const char*)&Bl[c][0] + row * 64 + p * 16);
    }
    asm volatile("s_waitcnt lgkmcnt(0)" ::: "memory");
    __builtin_amdgcn_sched_barrier(0);
    __builtin_amdgcn_s_barrier();          // all waves done reading buf c

    if (t + 2 < nt) stage(t + 2, c);       // refill freed buffer (async)

#pragma unroll
    for (int mi = 0; mi < MI; ++mi)
#pragma unroll
      for (int ni = 0; ni < NI; ++ni)
        acc[mi][ni] = __builtin_amdgcn_mfma_f32_16x16x32_bf16(af[mi], bfv[ni],
                                                              acc[mi][ni], 0, 0, 0);

    if (t + 1 < nt) {
      if (t + 2 < nt)
        asm volatile("s_waitcnt vmcnt(6)" ::: "memory");  // t+1 landed; t+2 in flight
      else
        asm volatile("s_waitcnt vmcnt(0)" ::: "memory");  // tail drain
      __builtin_amdgcn_s_barrier();
    }
  }

  // ---- epilogue: C/D layout col=lane&15, row=(lane>>4)*4+reg ----
  __bf16* cbase = Cout + (size_t)blockIdx.z * M * N;
#pragma unroll
  for (int ni = 0; ni < NI; ++ni) {
    int col = n0 + wc * 64 + ni * 16 + l15;
#pragma unroll
    for (int mi = 0; mi < MI; ++mi) {
#pragma unroll
      for (int r = 0; r < 4; ++r) {
        int row = m0 + wr * 64 + mi * 16 + lhi * 4 + r;
        cbase[(size_t)row * N + col] = (__bf16)acc[mi][ni][r];
      }
    }
  }
}

// ==================== GEMM2: counted-vmcnt 2-phase pipeline ====================
// C[M,N] = Amat[M,K] @ Bmat[N,K]^T + bias, f32 out. BK=32, dbuf LDS 32 KB
// (bf16 8K x4) -> 5 blocks/CU. 4 staging issues/tile -> vmcnt(4).
__global__ __launch_bounds__(256) void gemm2_pipe(const __bf16* __restrict__ Amat,
                                                  const __bf16* __restrict__ Bmat,
                                                  const float* __restrict__ bias,
                                                  float* __restrict__ Cout,
                                                  int M, int N, int K) {
  constexpr int BM = 128, BN = 128, BK = 32;
  constexpr int MI = 4, NI = 4;
  __shared__ alignas(16) __bf16 Al[2][BM * BK];
  __shared__ alignas(16) __bf16 Bl[2][BN * BK];

  const int tid = threadIdx.x;
  const int wid = tid >> 6;
  const int lane = tid & 63;
  const int l15 = lane & 15, lhi = lane >> 4;
  const int wr = wid >> 1, wc = wid & 1;

  const int m0 = blockIdx.x * BM;
  const int n0 = blockIdx.y * BN;
  const int nt = K / BK;   // 16

  f32x4 acc[MI][NI] = {};

  auto stage = [&](int t, int c) {
    const int k0 = t * BK;
#pragma unroll
    for (int it = 0; it < 2; ++it) {
      int o = (it * 256 + tid) * 8;
      int row = o >> 5;
      int b = (o & 31) >> 3;
      int colsw = (b ^ ((row >> 1) & 3)) * 8;
      gload_lds16(Amat + (size_t)(m0 + row) * K + k0 + colsw,
                  &Al[c][(it * 256 + wid * 64) * 8]);
    }
#pragma unroll
    for (int it = 0; it < 2; ++it) {
      int o = (it * 256 + tid) * 8;
      int row = o >> 5;
      int b = (o & 31) >> 3;
      int colsw = (b ^ ((row >> 1) & 3)) * 8;
      gload_lds16(Bmat + (size_t)(n0 + row) * K + k0 + colsw,
                  &Bl[c][(it * 256 + wid * 64) * 8]);
    }
  };

  stage(0, 0);
  stage(1, 1);
  asm volatile("s_waitcnt vmcnt(4)" ::: "memory");
  __builtin_amdgcn_s_barrier();

  for (int t = 0; t < nt; ++t) {
    const int c = t & 1;
    bf16x8 af[MI];
    bf16x8 bfv[NI];
#pragma unroll
    for (int mi = 0; mi < MI; ++mi) {
      int row = wr * 64 + mi * 16 + l15;
      int p = lhi ^ ((row >> 1) & 3);
      af[mi] = *(const bf16x8*)((const char*)&Al[c][0] + row * 64 + p * 16);
    }
#pragma unroll
    for (int ni = 0; ni < NI; ++ni) {
      int row = wc * 64 + ni * 16 + l15;
      int p = lhi ^ ((row >> 1) & 3);
      bfv[ni] = *(const bf16x8*)((const char*)&Bl[c][0] + row * 64 + p * 16);
    }
    asm volatile("s_waitcnt lgkmcnt(0)" ::: "memory");
    __builtin_amdgcn_sched_barrier(0);
    __builtin_amdgcn_s_barrier();

    if (t + 2 < nt) stage(t + 2, c);

#pragma unroll
    for (int mi = 0; mi < MI; ++mi)
#pragma unroll
      for (int ni = 0; ni < NI; ++ni)
        acc[mi][ni] = __builtin_amdgcn_mfma_f32_16x16x32_bf16(af[mi], bfv[ni],
                                                              acc[mi][ni], 0, 0, 0);

    if (t + 1 < nt) {
      if (t + 2 < nt)
        asm volatile("s_waitcnt vmcnt(4)" ::: "memory");
      else
        asm volatile("s_waitcnt vmcnt(0)" ::: "memory");
      __builtin_amdgcn_s_barrier();
    }
  }

#pragma unroll
  for (int ni = 0; ni < NI; ++ni) {
    int col = n0 + wc * 64 + ni * 16 + l15;
    float bv = bias[col];
#pragma unroll
    for (int mi = 0; mi < MI; ++mi) {
#pragma unroll
      for (int r = 0; r < 4; ++r) {
        int row = m0 + wr * 64 + mi * 16 + lhi * 4 + r;
        Cout[(size_t)row * N + col] = acc[mi][ni][r] + bv;
      }
    }
  }
}

extern "C" void kernel_launch(void* const* d_in, const int* in_sizes, int n_in,
                              void* d_out, int out_size, void* d_ws, size_t ws_size,
                              hipStream_t stream) {
  const float* x    = (const float*)d_in[0];
  const float* A    = (const float*)d_in[1];
  const float* B    = (const float*)d_in[2];
  const float* bias = (const float*)d_in[3];
  float* out = (float*)d_out;

  // d_out doubles as scratch before GEMM2 overwrites it:
  //   [64, 80 MiB) : tp = split-K partials (consumed by reduce2)
  __bf16* tp = (__bf16*)((char*)d_out + ((size_t)64 << 20));
  char* ws = (char*)d_ws;
  __bf16* Ab = (__bf16*)ws;                        // [D_OUT][RANK] bf16
  __bf16* Bt = (__bf16*)(ws + ((size_t)4 << 20));  // [RANK][D_IN]  bf16
  __bf16* Tt = (__bf16*)(ws + ((size_t)8 << 20));  // [MROWS][RANK] bf16

  hipLaunchKernelGGL(cvt_f32_bf16, dim3(512), dim3(256), 0, stream,
                     A, Ab, (size_t)D_OUT * RANK);
  hipLaunchKernelGGL(transpose_cvt, dim3(D_IN / 64, RANK / 64), dim3(256), 0, stream,
                     B, Bt, D_IN, RANK);
  // t_partial[z] = bf16(x) @ B[:, z*2048:(z+1)*2048]  (fused cast, split-K=2)
  hipLaunchKernelGGL(gemm1_pipe,
                     dim3(MROWS / 128, RANK / 128, 2), dim3(256), 0, stream,
                     x, Bt, tp, MROWS, RANK, D_IN / 2, D_IN);
  // Tt = bf16(tp[0] + tp[1])
  hipLaunchKernelGGL(reduce2_bf16, dim3(MROWS * RANK / (256 * 8)), dim3(256), 0, stream,
                     tp, tp + (size_t)MROWS * RANK, Tt);
  // out = Tt @ A^T + bias
  hipLaunchKernelGGL(gemm2_pipe,
                     dim3(MROWS / 128, D_OUT / 128), dim3(256), 0, stream,
                     Tt, Ab, bias, out, MROWS, D_OUT, RANK);
}